// Round 19
// baseline (127.966 us; speedup 1.0000x reference)
//
#include <hip/hip_runtime.h>
#include <hip/hip_bf16.h>
#include <math.h>

#define D 2
#define B 64
#define P 512
#define NV 64
#define H 64
#define TW 128
#define NQ (B*NV + B)   // 4160

typedef short short8 __attribute__((ext_vector_type(8)));
typedef short short4v __attribute__((ext_vector_type(4)));
typedef float f32x4 __attribute__((ext_vector_type(4)));
typedef int   int4v  __attribute__((ext_vector_type(4)));

static __device__ __forceinline__ unsigned short f2bf(float f) {
    unsigned int u = __builtin_bit_cast(unsigned int, f);
    u += 0x7FFFu + ((u >> 16) & 1u);          // RNE
    return (unsigned short)(u >> 16);
}
static __device__ __forceinline__ unsigned int pk2bf(float a, float b) {
    __hip_bfloat162 h = __float22bfloat162_rn(make_float2(a, b));  // v_cvt_pk_bf16_f32
    unsigned int u;
    __builtin_memcpy(&u, &h, 4);              // a -> low 16, b -> high 16
    return u;
}

// ---------------- Kernel A: coeff (attention) ----------------
// R19 = R16 per-wave body, 8 queries per 1024-thread block (16 waves).
// Tests the last unexplained cap: occupancy frozen at ~8 waves/CU across all
// VGPR/LDS configs -> suspected per-CU BLOCK-count limit (~2). Packing 16
// waves/block makes 2 blocks/CU = 32 waves/CU. Per-wave code identical to
// R16 (best coeff 58.2us). Weights in LDS; only afrag register-pinned.
__global__ __launch_bounds__(1024) void coeff_kernel(
    const float* __restrict__ coords, const float* __restrict__ vel,
    const float* __restrict__ pos, const float* __restrict__ sigma,
    const float* __restrict__ aW0, const float* __restrict__ ab0,
    const float* __restrict__ aW1, const float* __restrict__ ab1,
    const float* __restrict__ aW2, const float* __restrict__ ab2,
    float* __restrict__ coeff_out)
{
    __shared__ unsigned short s_w1t[64*72];   // aW1^T [n][k] bf16, stride 72
    __shared__ float2 s_pos[P];
    __shared__ float  s_logit[8][512];        // per-query masked logits
    __shared__ float  s_cw[4*64];             // w4 | w5 | b1 | w2 (query-indep)
    __shared__ float  s_base[8][64];          // per-query collapsed layer1 base

    const int tid  = threadIdx.x;
    const int lane = tid & 63, wid = tid >> 6;
    const int l15 = lane & 15, lg = lane >> 4;
    const int qi   = wid >> 1;                // query index within block (0..7)
    const int half = wid & 1;                 // position half (0: 0-255, 1: 256-511)
    const int q = blockIdx.x*8 + qi;

    // ---- block-wide staging
    for (int i = tid; i < H*H; i += 1024) {
        const int k = i >> 6, n = i & 63;
        s_w1t[n*72 + k] = f2bf(aW1[i]);
    }
    if (tid < 256) {
        const float4 p4 = ((const float4*)pos)[tid];
        *(float4*)&s_pos[tid*2] = p4;
        if (tid < 64)        s_cw[tid] = aW0[256 + tid];        // w4
        else if (tid < 128)  s_cw[tid] = aW0[320 + (tid-64)];   // w5
        else if (tid < 192)  s_cw[tid] = ab1[tid-128];          // b1
        else                 s_cw[tid] = aW2[tid-192];          // w2
    }

    // ---- per-wave query scalars
    float x0, x1, v0, v1;
    {
        int b;
        if (q < B*NV) { b = q >> 6; const int j = q & 63;
            v0 = vel[2*j]; v1 = vel[2*j+1];
        } else { b = q - B*NV;
            v0 = coords[4*b+2]; v1 = coords[4*b+3];
        }
        x0 = coords[4*b]; x1 = coords[4*b+1];
    }
    const float rinv = rsqrtf(v0*v0 + v1*v1 + 1e-16f);
    const float a0 = v0*rinv, a1 = v1*rinv;

    // ---- per-query collapsed base (computed once by the half==0 wave)
    if (half == 0) {
        const int k = lane;
        s_base[qi][k] = ab0[k] + x0*aW0[k] + x1*aW0[64+k]
                      + v0*aW0[128+k] + v1*aW0[192+k];
    }
    __syncthreads();

    // ---- A fragments: aW1^T rows = n, persistent (only pinned register set)
    short8 afrag[4][2];
    #pragma unroll
    for (int nt = 0; nt < 4; ++nt)
        #pragma unroll
        for (int ks = 0; ks < 2; ++ks)
            afrag[nt][ks] = *(const short8*)&s_w1t[(nt*16 + l15)*72 + ks*32 + lg*8];
    #pragma unroll
    for (int nt = 0; nt < 4; ++nt)
        asm volatile("" : "+v"(afrag[nt][0]), "+v"(afrag[nt][1]));

    const float* bq = s_base[qi];
    const int k0 = lg*8;

    // ---- 16 passes of 16 positions; geometry software-pipelined one ahead
    float pl, al;
    {
        const float2 p0v = s_pos[half*256 + l15];
        const float rx = x0 - p0v.x, ry = x1 - p0v.y;
        const float rd = __builtin_amdgcn_sqrtf(rx*rx + ry*ry + 1e-16f);
        pl = rx*a0 + ry*a1;
        al = __fdividef(pl, rd + 1e-8f);
    }
    for (int ps = 0; ps < 16; ++ps) {
        const int prow = half*256 + ps*16 + l15;
        float pln = pl, aln = al;
        if (ps < 15) {
            const float2 nxt = s_pos[prow + 16];
            const float rxn = x0 - nxt.x, ryn = x1 - nxt.y;
            const float rdn = __builtin_amdgcn_sqrtf(rxn*rxn + ryn*ryn + 1e-16f);
            pln = rxn*a0 + ryn*a1;
            aln = __fdividef(pln, rdn + 1e-8f);
        }

        // layer1 from LDS (broadcast f32x4 reads) directly into B-fragments
        const f32x4 w4A = *(const f32x4*)&s_cw[k0];
        const f32x4 w4B = *(const f32x4*)&s_cw[k0+4];
        const f32x4 w4C = *(const f32x4*)&s_cw[k0+32];
        const f32x4 w4D = *(const f32x4*)&s_cw[k0+36];
        const f32x4 w5A = *(const f32x4*)&s_cw[64+k0];
        const f32x4 w5B = *(const f32x4*)&s_cw[64+k0+4];
        const f32x4 w5C = *(const f32x4*)&s_cw[64+k0+32];
        const f32x4 w5D = *(const f32x4*)&s_cw[64+k0+36];
        const f32x4 bA  = *(const f32x4*)&bq[k0];
        const f32x4 bB  = *(const f32x4*)&bq[k0+4];
        const f32x4 bC  = *(const f32x4*)&bq[k0+32];
        const f32x4 bD  = *(const f32x4*)&bq[k0+36];

        f32x4 rA, rB, rC, rD;
        #pragma unroll
        for (int c = 0; c < 4; ++c) {
            rA[c] = fmaxf(fmaf(pl, w5A[c], fmaf(al, w4A[c], bA[c])), 0.f);
            rB[c] = fmaxf(fmaf(pl, w5B[c], fmaf(al, w4B[c], bB[c])), 0.f);
            rC[c] = fmaxf(fmaf(pl, w5C[c], fmaf(al, w4C[c], bC[c])), 0.f);
            rD[c] = fmaxf(fmaf(pl, w5D[c], fmaf(al, w4D[c], bD[c])), 0.f);
        }
        int4v wlo, whi;
        wlo[0] = (int)pk2bf(rA[0], rA[1]);
        wlo[1] = (int)pk2bf(rA[2], rA[3]);
        wlo[2] = (int)pk2bf(rB[0], rB[1]);
        wlo[3] = (int)pk2bf(rB[2], rB[3]);
        whi[0] = (int)pk2bf(rC[0], rC[1]);
        whi[1] = (int)pk2bf(rC[2], rC[3]);
        whi[2] = (int)pk2bf(rD[0], rD[1]);
        whi[3] = (int)pk2bf(rD[2], rD[3]);
        const short8 bf0 = __builtin_bit_cast(short8, wlo);
        const short8 bf1 = __builtin_bit_cast(short8, whi);

        float ssum = 0.f;
        #pragma unroll
        for (int nt = 0; nt < 4; ++nt) {
            const int n0 = nt*16 + lg*4;
            f32x4 acc = *(const f32x4*)&s_cw[128 + n0];   // b1 C-init (LDS broadcast)
            acc = __builtin_amdgcn_mfma_f32_16x16x32_bf16(afrag[nt][0], bf0, acc, 0, 0, 0);
            acc = __builtin_amdgcn_mfma_f32_16x16x32_bf16(afrag[nt][1], bf1, acc, 0, 0, 0);
            const f32x4 w2x = *(const f32x4*)&s_cw[192 + n0];
            ssum += fmaxf(acc[0], 0.f) * w2x[0];
            ssum += fmaxf(acc[1], 0.f) * w2x[1];
            ssum += fmaxf(acc[2], 0.f) * w2x[2];
            ssum += fmaxf(acc[3], 0.f) * w2x[3];
        }
        ssum += __shfl_xor(ssum, 16, 64);
        ssum += __shfl_xor(ssum, 32, 64);
        if (lane < 16) s_logit[qi][prow] = (pl > 0.f) ? ssum : -1e30f;
        pl = pln; al = aln;
    }
    __syncthreads();

    // ---- softmax + sigma dot (wave-pair-redundant, bit-identical)
    const float* lgb = s_logit[qi];
    const float4 l0 = *(const float4*)&lgb[lane*8];
    const float4 l1 = *(const float4*)&lgb[lane*8 + 4];
    float m = fmaxf(fmaxf(fmaxf(l0.x, l0.y), fmaxf(l0.z, l0.w)),
                    fmaxf(fmaxf(l1.x, l1.y), fmaxf(l1.z, l1.w)));
    #pragma unroll
    for (int o = 32; o > 0; o >>= 1) m = fmaxf(m, __shfl_xor(m, o, 64));

    const float4 g0 = *(const float4*)&sigma[lane*8];
    const float4 g1 = *(const float4*)&sigma[lane*8 + 4];
    float S = 0.f, T = 0.f, e;
    e = __expf(l0.x - m); S += e; T += e*g0.x;
    e = __expf(l0.y - m); S += e; T += e*g0.y;
    e = __expf(l0.z - m); S += e; T += e*g0.z;
    e = __expf(l0.w - m); S += e; T += e*g0.w;
    e = __expf(l1.x - m); S += e; T += e*g1.x;
    e = __expf(l1.y - m); S += e; T += e*g1.y;
    e = __expf(l1.z - m); S += e; T += e*g1.z;
    e = __expf(l1.w - m); S += e; T += e*g1.w;
    #pragma unroll
    for (int o = 32; o > 0; o >>= 1) { S += __shfl_xor(S, o, 64); T += __shfl_xor(T, o, 64); }
    if (lane == 0 && half == 0) coeff_out[q] = __expf(-(T / S));
}

// ---------------- Kernel B: transport MLP (MFMA, 64 queries/block) ----------------
__global__ __launch_bounds__(512) void transport_kernel(
    const float* __restrict__ coords, const float* __restrict__ coordsp,
    const float* __restrict__ vel,
    const float* __restrict__ tW0, const float* __restrict__ tb0,
    const float* __restrict__ tW1, const float* __restrict__ tb1,
    const float* __restrict__ tW2, const float* __restrict__ tb2,
    const float* __restrict__ coeff_ws, float* __restrict__ cur_ws,
    float* __restrict__ g_ws)
{
    __shared__ unsigned short s_w0t[128*40];
    __shared__ unsigned short s_wt[128*136];
    __shared__ unsigned short s_in[64*40];
    __shared__ unsigned short s_ha[64*136];
    __shared__ unsigned short s_hb[64*136];
    __shared__ float s_b[3*128];

    const int tid = threadIdx.x, g = blockIdx.x;
    const int lane = tid & 63, wid = tid >> 6;
    const int wm = wid & 3, wn = wid >> 2;
    const int l15 = lane & 15, lg = lane >> 4;
    const int irow = wm*16 + lg*4;
    const int qbase = g*64;

    for (int i = tid; i < 128*40; i += 512) {
        const int t = i / 40, k = i % 40;
        s_w0t[i] = (k < 9) ? f2bf(tW0[k*TW + t]) : 0;
    }
    for (int i = tid; i < 64*40; i += 512) s_in[i] = 0;
    {
        const int n = tid & 127, u0 = (tid >> 7)*4;
        #pragma unroll
        for (int k8 = 0; k8 < 8; ++k8) {
            const int u = u0 + 16*k8;
            short4v pk;
            #pragma unroll
            for (int c = 0; c < 4; ++c) pk[c] = (short)f2bf(tW1[(u+c)*TW + n]);
            *(short4v*)&s_wt[n*136 + u] = pk;
        }
    }
    if (tid < 128) { s_b[tid] = tb0[tid]; s_b[128+tid] = tb1[tid]; s_b[256+tid] = tb2[tid]; }
    __syncthreads();

    if (tid < 64) {
        const int q = qbase + tid;
        int b; float v0, v1;
        if (q < B*NV) { b = q >> 6; const int j = q & 63;
            v0 = vel[2*j]; v1 = vel[2*j+1];
        } else { b = q - B*NV;
            v0 = coords[4*b+2]; v1 = coords[4*b+3];
        }
        unsigned short* r = &s_in[tid*40];
        r[0] = f2bf(coords[4*b]);   r[1] = f2bf(coords[4*b+1]);
        r[2] = f2bf(v0);            r[3] = f2bf(v1);
        r[4] = f2bf(coordsp[4*b]);  r[5] = f2bf(coordsp[4*b+1]);
        r[6] = f2bf(coordsp[4*b+2]);r[7] = f2bf(coordsp[4*b+3]);
        r[8] = f2bf(coeff_ws[q]);
    }
    __syncthreads();

    {
        const short8 a0 = *(const short8*)&s_in[(wm*16 + l15)*40 + lg*8];
        #pragma unroll
        for (int nt = 0; nt < 4; ++nt) {
            const int col = wn*64 + nt*16 + l15;
            const short8 b0f = *(const short8*)&s_w0t[col*40 + lg*8];
            const float bias = s_b[col];
            f32x4 acc = { bias, bias, bias, bias };
            acc = __builtin_amdgcn_mfma_f32_16x16x32_bf16(a0, b0f, acc, 0, 0, 0);
            #pragma unroll
            for (int rg = 0; rg < 4; ++rg)
                s_ha[(irow + rg)*136 + col] = f2bf(fmaxf(acc[rg], 0.f));
        }
    }
    __syncthreads();

    {
        short8 af[4];
        #pragma unroll
        for (int ks = 0; ks < 4; ++ks)
            af[ks] = *(const short8*)&s_ha[(wm*16 + l15)*136 + ks*32 + lg*8];
        #pragma unroll
        for (int nt = 0; nt < 4; ++nt) {
            const int col = wn*64 + nt*16 + l15;
            const float bias = s_b[128 + col];
            f32x4 acc = { bias, bias, bias, bias };
            #pragma unroll
            for (int ks = 0; ks < 4; ++ks) {
                const short8 bfr = *(const short8*)&s_wt[col*136 + ks*32 + lg*8];
                acc = __builtin_amdgcn_mfma_f32_16x16x32_bf16(af[ks], bfr, acc, 0, 0, 0);
            }
            #pragma unroll
            for (int rg = 0; rg < 4; ++rg)
                s_hb[(irow + rg)*136 + col] = f2bf(fmaxf(acc[rg], 0.f));
        }
    }
    __syncthreads();

    {
        const int n = tid & 127, u0 = (tid >> 7)*4;
        #pragma unroll
        for (int k8 = 0; k8 < 8; ++k8) {
            const int u = u0 + 16*k8;
            short4v pk;
            #pragma unroll
            for (int c = 0; c < 4; ++c) pk[c] = (short)f2bf(tW2[(u+c)*TW + n]);
            *(short4v*)&s_wt[n*136 + u] = pk;
        }
    }
    __syncthreads();

    {
        short8 af[4];
        #pragma unroll
        for (int ks = 0; ks < 4; ++ks)
            af[ks] = *(const short8*)&s_hb[(wm*16 + l15)*136 + ks*32 + lg*8];
        #pragma unroll
        for (int nt = 0; nt < 4; ++nt) {
            const int col = wn*64 + nt*16 + l15;
            const float bias = s_b[256 + col];
            f32x4 acc = { bias, bias, bias, bias };
            #pragma unroll
            for (int ks = 0; ks < 4; ++ks) {
                const short8 bfr = *(const short8*)&s_wt[col*136 + ks*32 + lg*8];
                acc = __builtin_amdgcn_mfma_f32_16x16x32_bf16(af[ks], bfr, acc, 0, 0, 0);
            }
            #pragma unroll
            for (int rg = 0; rg < 4; ++rg) {
                const float o = __expf(fmaxf(acc[rg], 0.f));
                const int q = qbase + irow + rg;
                if (q < B*NV) cur_ws[q*TW + col] = o;
                else          g_ws[(q - B*NV)*TW + col] = o;
            }
        }
    }
}

// ---------------- Kernel C: scattering recursion + output (MFMA) ----------------
__global__ __launch_bounds__(512) void scatter_kernel(
    const float* __restrict__ scat_k, const float* __restrict__ vw,
    const float* __restrict__ ssk,
    const float* __restrict__ rW, const float* __restrict__ rb,
    const float* __restrict__ fW, const float* __restrict__ fb,
    const float* __restrict__ cur_ws, const float* __restrict__ g_ws,
    float* __restrict__ out)
{
    __shared__ unsigned short s_At[128*72];
    __shared__ unsigned short s_r[64*136];
    __shared__ unsigned short s_rWt[128*136];
    __shared__ float s_wl[NV];
    __shared__ float s_fin[4*128];
    __shared__ float s_red[2];

    const int tid = threadIdx.x, b = blockIdx.x;
    const int lane = tid & 63, wid = tid >> 6;
    const int wm = wid & 3, wn = wid >> 2;
    const int l15 = lane & 15, lg = lane >> 4;
    const int irow = wm*16 + lg*4;

    if (tid < NV) s_wl[tid] = (1.f - scat_k[b*NV + tid]) * vw[tid];

    {
        const int w = tid & 127, j0 = tid >> 7;
        #pragma unroll
        for (int k = 0; k < 16; ++k) {
            const int j = j0 + 4*k;
            s_At[w*72 + j] = f2bf(cur_ws[(b*NV + j)*TW + w]);
        }
    }

    float areg[4][4], sreg[4][4];
    #pragma unroll
    for (int n = 0; n < 4; ++n) {
        const int wcol = wn*64 + n*16 + l15;
        #pragma unroll
        for (int rg = 0; rg < 4; ++rg) {
            const float v = cur_ws[(b*NV + irow + rg)*TW + wcol];
            areg[n][rg] = v; sreg[n][rg] = v;
        }
    }

    for (int l = 0; l < 2; ++l) {
        {
            const float* rWl = rW + l*TW*TW;
            const int w = tid & 127, u0 = (tid >> 7)*4;
            #pragma unroll
            for (int k = 0; k < 8; ++k) {
                const int u = u0 + 16*k;
                short4v pk;
                #pragma unroll
                for (int c = 0; c < 4; ++c) pk[c] = (short)f2bf(rWl[(u+c)*TW + w]);
                *(short4v*)&s_rWt[w*136 + u] = pk;
            }
        }
        __syncthreads();

        {
            short8 afrag[2];
            const int row = wm*16 + l15;
            #pragma unroll
            for (int ks = 0; ks < 2; ++ks) {
                const int k0 = ks*32 + lg*8;
                #pragma unroll
                for (int j = 0; j < 8; ++j) {
                    const float rv = (1.f - ssk[row*NV + k0 + j]) * vw[k0 + j];
                    afrag[ks][j] = (short)f2bf(rv);
                }
            }
            #pragma unroll
            for (int n = 0; n < 4; ++n) {
                const int col = wn*64 + n*16 + l15;
                f32x4 acc = {0.f, 0.f, 0.f, 0.f};
                #pragma unroll
                for (int ks = 0; ks < 2; ++ks) {
                    const short8 bfr = *(const short8*)&s_At[col*72 + ks*32 + lg*8];
                    acc = __builtin_amdgcn_mfma_f32_16x16x32_bf16(afrag[ks], bfr, acc, 0, 0, 0);
                }
                #pragma unroll
                for (int rg = 0; rg < 4; ++rg)
                    s_r[(irow + rg)*136 + col] = f2bf(acc[rg]);
            }
        }
        __syncthreads();

        {
            short8 af2[4];
            #pragma unroll
            for (int ks = 0; ks < 4; ++ks)
                af2[ks] = *(const short8*)&s_r[(wm*16 + l15)*136 + ks*32 + lg*8];
            #pragma unroll
            for (int n = 0; n < 4; ++n) {
                const int col = wn*64 + n*16 + l15;
                f32x4 acc = {0.f, 0.f, 0.f, 0.f};
                #pragma unroll
                for (int ks = 0; ks < 4; ++ks) {
                    const short8 bfr = *(const short8*)&s_rWt[col*136 + ks*32 + lg*8];
                    acc = __builtin_amdgcn_mfma_f32_16x16x32_bf16(af2[ks], bfr, acc, 0, 0, 0);
                }
                const float rbv = rb[l*TW + col];
                short4v pk;
                #pragma unroll
                for (int rg = 0; rg < 4; ++rg) {
                    areg[n][rg] += fmaxf(acc[rg] + rbv, 0.f);
                    sreg[n][rg] += areg[n][rg];
                    pk[rg] = (short)f2bf(areg[n][rg]);
                }
                *(short4v*)&s_At[col*72 + irow] = pk;
            }
        }
        __syncthreads();
    }

    float p[4];
    #pragma unroll
    for (int n = 0; n < 4; ++n) {
        float acc = 0.f;
        #pragma unroll
        for (int rg = 0; rg < 4; ++rg) acc += s_wl[irow + rg] * sreg[n][rg];
        acc += __shfl_xor(acc, 16, 64);
        acc += __shfl_xor(acc, 32, 64);
        p[n] = acc;
    }
    if (lg == 0) {
        #pragma unroll
        for (int n = 0; n < 4; ++n)
            s_fin[wm*128 + wn*64 + n*16 + l15] = p[n];
    }
    __syncthreads();

    if (tid < 128) {
        const int w = tid;
        const float tot = s_fin[w] + s_fin[128 + w] + s_fin[256 + w] + s_fin[384 + w];
        float pw = (g_ws[b*TW + w] + tot) * fW[w];
        #pragma unroll
        for (int o = 32; o > 0; o >>= 1) pw += __shfl_down(pw, o, 64);
        if ((tid & 63) == 0) s_red[tid >> 6] = pw;
    }
    __syncthreads();
    if (tid == 0) out[b] = s_red[0] + s_red[1] + fb[0];
}

extern "C" void kernel_launch(void* const* d_in, const int* in_sizes, int n_in,
                              void* d_out, int out_size, void* d_ws, size_t ws_size,
                              hipStream_t stream) {
    const float* coords  = (const float*)d_in[0];
    const float* coordsp = (const float*)d_in[1];
    const float* scatk   = (const float*)d_in[2];
    const float* pos     = (const float*)d_in[3];
    const float* sigma   = (const float*)d_in[4];
    const float* vel     = (const float*)d_in[5];
    const float* vw      = (const float*)d_in[6];
    const float* ssk     = (const float*)d_in[7];
    const float* aW0 = (const float*)d_in[8];
    const float* ab0 = (const float*)d_in[9];
    const float* aW1 = (const float*)d_in[10];
    const float* ab1 = (const float*)d_in[11];
    const float* aW2 = (const float*)d_in[12];
    const float* ab2 = (const float*)d_in[13];
    const float* tW0 = (const float*)d_in[14];
    const float* tb0 = (const float*)d_in[15];
    const float* tW1 = (const float*)d_in[16];
    const float* tb1 = (const float*)d_in[17];
    const float* tW2 = (const float*)d_in[18];
    const float* tb2 = (const float*)d_in[19];
    const float* rW  = (const float*)d_in[20];
    const float* rb  = (const float*)d_in[21];
    const float* fW  = (const float*)d_in[22];
    const float* fb  = (const float*)d_in[23];
    float* out = (float*)d_out;

    float* ws = (float*)d_ws;
    float* coeff_ws = ws;                    // NQ floats, padded
    float* cur_ws   = ws + 4224;             // B*NV*TW floats
    float* g_ws     = cur_ws + B*NV*TW;      // B*TW floats

    hipLaunchKernelGGL(coeff_kernel, dim3(NQ/8), dim3(1024), 0, stream,
        coords, vel, pos, sigma, aW0, ab0, aW1, ab1, aW2, ab2, coeff_ws);
    hipLaunchKernelGGL(transport_kernel, dim3(NQ/64), dim3(512), 0, stream,
        coords, coordsp, vel, tW0, tb0, tW1, tb1, tW2, tb2, coeff_ws, cur_ws, g_ws);
    hipLaunchKernelGGL(scatter_kernel, dim3(B), dim3(512), 0, stream,
        scatk, vw, ssk, rW, rb, fW, fb, cur_ws, g_ws, out);
}

// Round 20
// 84.781 us; speedup vs baseline: 1.5094x; 1.5094x over previous
//
#include <hip/hip_runtime.h>
#include <hip/hip_bf16.h>
#include <math.h>

#define D 2
#define B 64
#define P 512
#define NV 64
#define H 64
#define TW 128
#define NQ (B*NV + B)   // 4160

typedef short short8 __attribute__((ext_vector_type(8)));
typedef short short4v __attribute__((ext_vector_type(4)));
typedef float f32x4 __attribute__((ext_vector_type(4)));
typedef int   int4v  __attribute__((ext_vector_type(4)));

static __device__ __forceinline__ unsigned short f2bf(float f) {
    unsigned int u = __builtin_bit_cast(unsigned int, f);
    u += 0x7FFFu + ((u >> 16) & 1u);          // RNE
    return (unsigned short)(u >> 16);
}
static __device__ __forceinline__ unsigned int pk2bf(float a, float b) {
    __hip_bfloat162 h = __float22bfloat162_rn(make_float2(a, b));  // v_cvt_pk_bf16_f32
    unsigned int u;
    __builtin_memcpy(&u, &h, 4);              // a -> low 16, b -> high 16
    return u;
}

// ---------------- Kernel A: coeff (attention) ----------------
// R20 = R16 per-wave body, 4 queries per 512-thread block (8 waves).
// R19 proved waves/CU scales with block size (occ 25->31%) but 1024-thread
// blocks forced a 64-VGPR target -> 51MB spill. 512 threads keeps natural
// ~80-VGPR allocation (no spill) while doubling waves/block: at the observed
// ~2-blocks/CU scheduler cap -> 16 waves/CU = 50% occupancy.
// No min-waves bound (R4/R7/R17/R19: every forced-VGPR config spilled).
__global__ __launch_bounds__(512) void coeff_kernel(
    const float* __restrict__ coords, const float* __restrict__ vel,
    const float* __restrict__ pos, const float* __restrict__ sigma,
    const float* __restrict__ aW0, const float* __restrict__ ab0,
    const float* __restrict__ aW1, const float* __restrict__ ab1,
    const float* __restrict__ aW2, const float* __restrict__ ab2,
    float* __restrict__ coeff_out)
{
    __shared__ unsigned short s_w1t[64*72];   // aW1^T [n][k] bf16, stride 72
    __shared__ float2 s_pos[P];
    __shared__ float  s_logit[4][512];        // per-query masked logits
    __shared__ float  s_cw[4*64];             // w4 | w5 | b1 | w2 (query-indep)
    __shared__ float  s_base[4][64];          // per-query collapsed layer1 base

    const int tid  = threadIdx.x;
    const int lane = tid & 63, wid = tid >> 6;
    const int l15 = lane & 15, lg = lane >> 4;
    const int qi   = wid >> 1;                // query index within block (0..3)
    const int half = wid & 1;                 // position half (0: 0-255, 1: 256-511)
    const int q = blockIdx.x*4 + qi;

    // ---- block-wide staging
    for (int i = tid; i < H*H; i += 512) {
        const int k = i >> 6, n = i & 63;
        s_w1t[n*72 + k] = f2bf(aW1[i]);
    }
    if (tid < 256) {
        const float4 p4 = ((const float4*)pos)[tid];
        *(float4*)&s_pos[tid*2] = p4;
        if (tid < 64)        s_cw[tid] = aW0[256 + tid];        // w4
        else if (tid < 128)  s_cw[tid] = aW0[320 + (tid-64)];   // w5
        else if (tid < 192)  s_cw[tid] = ab1[tid-128];          // b1
        else                 s_cw[tid] = aW2[tid-192];          // w2
    }

    // ---- per-wave query scalars
    float x0, x1, v0, v1;
    {
        int b;
        if (q < B*NV) { b = q >> 6; const int j = q & 63;
            v0 = vel[2*j]; v1 = vel[2*j+1];
        } else { b = q - B*NV;
            v0 = coords[4*b+2]; v1 = coords[4*b+3];
        }
        x0 = coords[4*b]; x1 = coords[4*b+1];
    }
    const float rinv = rsqrtf(v0*v0 + v1*v1 + 1e-16f);
    const float a0 = v0*rinv, a1 = v1*rinv;

    // ---- per-query collapsed base (computed once by the half==0 wave)
    if (half == 0) {
        const int k = lane;
        s_base[qi][k] = ab0[k] + x0*aW0[k] + x1*aW0[64+k]
                      + v0*aW0[128+k] + v1*aW0[192+k];
    }
    __syncthreads();

    // ---- A fragments: aW1^T rows = n, persistent (only pinned register set)
    short8 afrag[4][2];
    #pragma unroll
    for (int nt = 0; nt < 4; ++nt)
        #pragma unroll
        for (int ks = 0; ks < 2; ++ks)
            afrag[nt][ks] = *(const short8*)&s_w1t[(nt*16 + l15)*72 + ks*32 + lg*8];
    #pragma unroll
    for (int nt = 0; nt < 4; ++nt)
        asm volatile("" : "+v"(afrag[nt][0]), "+v"(afrag[nt][1]));

    const float* bq = s_base[qi];
    const int k0 = lg*8;

    // ---- 16 passes of 16 positions; geometry software-pipelined one ahead
    float pl, al;
    {
        const float2 p0v = s_pos[half*256 + l15];
        const float rx = x0 - p0v.x, ry = x1 - p0v.y;
        const float rd = __builtin_amdgcn_sqrtf(rx*rx + ry*ry + 1e-16f);
        pl = rx*a0 + ry*a1;
        al = __fdividef(pl, rd + 1e-8f);
    }
    for (int ps = 0; ps < 16; ++ps) {
        const int prow = half*256 + ps*16 + l15;
        float pln = pl, aln = al;
        if (ps < 15) {
            const float2 nxt = s_pos[prow + 16];
            const float rxn = x0 - nxt.x, ryn = x1 - nxt.y;
            const float rdn = __builtin_amdgcn_sqrtf(rxn*rxn + ryn*ryn + 1e-16f);
            pln = rxn*a0 + ryn*a1;
            aln = __fdividef(pln, rdn + 1e-8f);
        }

        // layer1 from LDS (broadcast f32x4 reads) directly into B-fragments
        const f32x4 w4A = *(const f32x4*)&s_cw[k0];
        const f32x4 w4B = *(const f32x4*)&s_cw[k0+4];
        const f32x4 w4C = *(const f32x4*)&s_cw[k0+32];
        const f32x4 w4D = *(const f32x4*)&s_cw[k0+36];
        const f32x4 w5A = *(const f32x4*)&s_cw[64+k0];
        const f32x4 w5B = *(const f32x4*)&s_cw[64+k0+4];
        const f32x4 w5C = *(const f32x4*)&s_cw[64+k0+32];
        const f32x4 w5D = *(const f32x4*)&s_cw[64+k0+36];
        const f32x4 bA  = *(const f32x4*)&bq[k0];
        const f32x4 bB  = *(const f32x4*)&bq[k0+4];
        const f32x4 bC  = *(const f32x4*)&bq[k0+32];
        const f32x4 bD  = *(const f32x4*)&bq[k0+36];

        f32x4 rA, rB, rC, rD;
        #pragma unroll
        for (int c = 0; c < 4; ++c) {
            rA[c] = fmaxf(fmaf(pl, w5A[c], fmaf(al, w4A[c], bA[c])), 0.f);
            rB[c] = fmaxf(fmaf(pl, w5B[c], fmaf(al, w4B[c], bB[c])), 0.f);
            rC[c] = fmaxf(fmaf(pl, w5C[c], fmaf(al, w4C[c], bC[c])), 0.f);
            rD[c] = fmaxf(fmaf(pl, w5D[c], fmaf(al, w4D[c], bD[c])), 0.f);
        }
        int4v wlo, whi;
        wlo[0] = (int)pk2bf(rA[0], rA[1]);
        wlo[1] = (int)pk2bf(rA[2], rA[3]);
        wlo[2] = (int)pk2bf(rB[0], rB[1]);
        wlo[3] = (int)pk2bf(rB[2], rB[3]);
        whi[0] = (int)pk2bf(rC[0], rC[1]);
        whi[1] = (int)pk2bf(rC[2], rC[3]);
        whi[2] = (int)pk2bf(rD[0], rD[1]);
        whi[3] = (int)pk2bf(rD[2], rD[3]);
        const short8 bf0 = __builtin_bit_cast(short8, wlo);
        const short8 bf1 = __builtin_bit_cast(short8, whi);

        float ssum = 0.f;
        #pragma unroll
        for (int nt = 0; nt < 4; ++nt) {
            const int n0 = nt*16 + lg*4;
            f32x4 acc = *(const f32x4*)&s_cw[128 + n0];   // b1 C-init (LDS broadcast)
            acc = __builtin_amdgcn_mfma_f32_16x16x32_bf16(afrag[nt][0], bf0, acc, 0, 0, 0);
            acc = __builtin_amdgcn_mfma_f32_16x16x32_bf16(afrag[nt][1], bf1, acc, 0, 0, 0);
            const f32x4 w2x = *(const f32x4*)&s_cw[192 + n0];
            ssum += fmaxf(acc[0], 0.f) * w2x[0];
            ssum += fmaxf(acc[1], 0.f) * w2x[1];
            ssum += fmaxf(acc[2], 0.f) * w2x[2];
            ssum += fmaxf(acc[3], 0.f) * w2x[3];
        }
        ssum += __shfl_xor(ssum, 16, 64);
        ssum += __shfl_xor(ssum, 32, 64);
        if (lane < 16) s_logit[qi][prow] = (pl > 0.f) ? ssum : -1e30f;
        pl = pln; al = aln;
    }
    __syncthreads();

    // ---- softmax + sigma dot (wave-pair-redundant, bit-identical)
    const float* lgb = s_logit[qi];
    const float4 l0 = *(const float4*)&lgb[lane*8];
    const float4 l1 = *(const float4*)&lgb[lane*8 + 4];
    float m = fmaxf(fmaxf(fmaxf(l0.x, l0.y), fmaxf(l0.z, l0.w)),
                    fmaxf(fmaxf(l1.x, l1.y), fmaxf(l1.z, l1.w)));
    #pragma unroll
    for (int o = 32; o > 0; o >>= 1) m = fmaxf(m, __shfl_xor(m, o, 64));

    const float4 g0 = *(const float4*)&sigma[lane*8];
    const float4 g1 = *(const float4*)&sigma[lane*8 + 4];
    float S = 0.f, T = 0.f, e;
    e = __expf(l0.x - m); S += e; T += e*g0.x;
    e = __expf(l0.y - m); S += e; T += e*g0.y;
    e = __expf(l0.z - m); S += e; T += e*g0.z;
    e = __expf(l0.w - m); S += e; T += e*g0.w;
    e = __expf(l1.x - m); S += e; T += e*g1.x;
    e = __expf(l1.y - m); S += e; T += e*g1.y;
    e = __expf(l1.z - m); S += e; T += e*g1.z;
    e = __expf(l1.w - m); S += e; T += e*g1.w;
    #pragma unroll
    for (int o = 32; o > 0; o >>= 1) { S += __shfl_xor(S, o, 64); T += __shfl_xor(T, o, 64); }
    if (lane == 0 && half == 0) coeff_out[q] = __expf(-(T / S));
}

// ---------------- Kernel B: transport MLP (MFMA, 64 queries/block) ----------------
__global__ __launch_bounds__(512) void transport_kernel(
    const float* __restrict__ coords, const float* __restrict__ coordsp,
    const float* __restrict__ vel,
    const float* __restrict__ tW0, const float* __restrict__ tb0,
    const float* __restrict__ tW1, const float* __restrict__ tb1,
    const float* __restrict__ tW2, const float* __restrict__ tb2,
    const float* __restrict__ coeff_ws, float* __restrict__ cur_ws,
    float* __restrict__ g_ws)
{
    __shared__ unsigned short s_w0t[128*40];
    __shared__ unsigned short s_wt[128*136];
    __shared__ unsigned short s_in[64*40];
    __shared__ unsigned short s_ha[64*136];
    __shared__ unsigned short s_hb[64*136];
    __shared__ float s_b[3*128];

    const int tid = threadIdx.x, g = blockIdx.x;
    const int lane = tid & 63, wid = tid >> 6;
    const int wm = wid & 3, wn = wid >> 2;
    const int l15 = lane & 15, lg = lane >> 4;
    const int irow = wm*16 + lg*4;
    const int qbase = g*64;

    for (int i = tid; i < 128*40; i += 512) {
        const int t = i / 40, k = i % 40;
        s_w0t[i] = (k < 9) ? f2bf(tW0[k*TW + t]) : 0;
    }
    for (int i = tid; i < 64*40; i += 512) s_in[i] = 0;
    {
        const int n = tid & 127, u0 = (tid >> 7)*4;
        #pragma unroll
        for (int k8 = 0; k8 < 8; ++k8) {
            const int u = u0 + 16*k8;
            short4v pk;
            #pragma unroll
            for (int c = 0; c < 4; ++c) pk[c] = (short)f2bf(tW1[(u+c)*TW + n]);
            *(short4v*)&s_wt[n*136 + u] = pk;
        }
    }
    if (tid < 128) { s_b[tid] = tb0[tid]; s_b[128+tid] = tb1[tid]; s_b[256+tid] = tb2[tid]; }
    __syncthreads();

    if (tid < 64) {
        const int q = qbase + tid;
        int b; float v0, v1;
        if (q < B*NV) { b = q >> 6; const int j = q & 63;
            v0 = vel[2*j]; v1 = vel[2*j+1];
        } else { b = q - B*NV;
            v0 = coords[4*b+2]; v1 = coords[4*b+3];
        }
        unsigned short* r = &s_in[tid*40];
        r[0] = f2bf(coords[4*b]);   r[1] = f2bf(coords[4*b+1]);
        r[2] = f2bf(v0);            r[3] = f2bf(v1);
        r[4] = f2bf(coordsp[4*b]);  r[5] = f2bf(coordsp[4*b+1]);
        r[6] = f2bf(coordsp[4*b+2]);r[7] = f2bf(coordsp[4*b+3]);
        r[8] = f2bf(coeff_ws[q]);
    }
    __syncthreads();

    {
        const short8 a0 = *(const short8*)&s_in[(wm*16 + l15)*40 + lg*8];
        #pragma unroll
        for (int nt = 0; nt < 4; ++nt) {
            const int col = wn*64 + nt*16 + l15;
            const short8 b0f = *(const short8*)&s_w0t[col*40 + lg*8];
            const float bias = s_b[col];
            f32x4 acc = { bias, bias, bias, bias };
            acc = __builtin_amdgcn_mfma_f32_16x16x32_bf16(a0, b0f, acc, 0, 0, 0);
            #pragma unroll
            for (int rg = 0; rg < 4; ++rg)
                s_ha[(irow + rg)*136 + col] = f2bf(fmaxf(acc[rg], 0.f));
        }
    }
    __syncthreads();

    {
        short8 af[4];
        #pragma unroll
        for (int ks = 0; ks < 4; ++ks)
            af[ks] = *(const short8*)&s_ha[(wm*16 + l15)*136 + ks*32 + lg*8];
        #pragma unroll
        for (int nt = 0; nt < 4; ++nt) {
            const int col = wn*64 + nt*16 + l15;
            const float bias = s_b[128 + col];
            f32x4 acc = { bias, bias, bias, bias };
            #pragma unroll
            for (int ks = 0; ks < 4; ++ks) {
                const short8 bfr = *(const short8*)&s_wt[col*136 + ks*32 + lg*8];
                acc = __builtin_amdgcn_mfma_f32_16x16x32_bf16(af[ks], bfr, acc, 0, 0, 0);
            }
            #pragma unroll
            for (int rg = 0; rg < 4; ++rg)
                s_hb[(irow + rg)*136 + col] = f2bf(fmaxf(acc[rg], 0.f));
        }
    }
    __syncthreads();

    {
        const int n = tid & 127, u0 = (tid >> 7)*4;
        #pragma unroll
        for (int k8 = 0; k8 < 8; ++k8) {
            const int u = u0 + 16*k8;
            short4v pk;
            #pragma unroll
            for (int c = 0; c < 4; ++c) pk[c] = (short)f2bf(tW2[(u+c)*TW + n]);
            *(short4v*)&s_wt[n*136 + u] = pk;
        }
    }
    __syncthreads();

    {
        short8 af[4];
        #pragma unroll
        for (int ks = 0; ks < 4; ++ks)
            af[ks] = *(const short8*)&s_hb[(wm*16 + l15)*136 + ks*32 + lg*8];
        #pragma unroll
        for (int nt = 0; nt < 4; ++nt) {
            const int col = wn*64 + nt*16 + l15;
            const float bias = s_b[256 + col];
            f32x4 acc = { bias, bias, bias, bias };
            #pragma unroll
            for (int ks = 0; ks < 4; ++ks) {
                const short8 bfr = *(const short8*)&s_wt[col*136 + ks*32 + lg*8];
                acc = __builtin_amdgcn_mfma_f32_16x16x32_bf16(af[ks], bfr, acc, 0, 0, 0);
            }
            #pragma unroll
            for (int rg = 0; rg < 4; ++rg) {
                const float o = __expf(fmaxf(acc[rg], 0.f));
                const int q = qbase + irow + rg;
                if (q < B*NV) cur_ws[q*TW + col] = o;
                else          g_ws[(q - B*NV)*TW + col] = o;
            }
        }
    }
}

// ---------------- Kernel C: scattering recursion + output (MFMA) ----------------
__global__ __launch_bounds__(512) void scatter_kernel(
    const float* __restrict__ scat_k, const float* __restrict__ vw,
    const float* __restrict__ ssk,
    const float* __restrict__ rW, const float* __restrict__ rb,
    const float* __restrict__ fW, const float* __restrict__ fb,
    const float* __restrict__ cur_ws, const float* __restrict__ g_ws,
    float* __restrict__ out)
{
    __shared__ unsigned short s_At[128*72];
    __shared__ unsigned short s_r[64*136];
    __shared__ unsigned short s_rWt[128*136];
    __shared__ float s_wl[NV];
    __shared__ float s_fin[4*128];
    __shared__ float s_red[2];

    const int tid = threadIdx.x, b = blockIdx.x;
    const int lane = tid & 63, wid = tid >> 6;
    const int wm = wid & 3, wn = wid >> 2;
    const int l15 = lane & 15, lg = lane >> 4;
    const int irow = wm*16 + lg*4;

    if (tid < NV) s_wl[tid] = (1.f - scat_k[b*NV + tid]) * vw[tid];

    {
        const int w = tid & 127, j0 = tid >> 7;
        #pragma unroll
        for (int k = 0; k < 16; ++k) {
            const int j = j0 + 4*k;
            s_At[w*72 + j] = f2bf(cur_ws[(b*NV + j)*TW + w]);
        }
    }

    float areg[4][4], sreg[4][4];
    #pragma unroll
    for (int n = 0; n < 4; ++n) {
        const int wcol = wn*64 + n*16 + l15;
        #pragma unroll
        for (int rg = 0; rg < 4; ++rg) {
            const float v = cur_ws[(b*NV + irow + rg)*TW + wcol];
            areg[n][rg] = v; sreg[n][rg] = v;
        }
    }

    for (int l = 0; l < 2; ++l) {
        {
            const float* rWl = rW + l*TW*TW;
            const int w = tid & 127, u0 = (tid >> 7)*4;
            #pragma unroll
            for (int k = 0; k < 8; ++k) {
                const int u = u0 + 16*k;
                short4v pk;
                #pragma unroll
                for (int c = 0; c < 4; ++c) pk[c] = (short)f2bf(rWl[(u+c)*TW + w]);
                *(short4v*)&s_rWt[w*136 + u] = pk;
            }
        }
        __syncthreads();

        {
            short8 afrag[2];
            const int row = wm*16 + l15;
            #pragma unroll
            for (int ks = 0; ks < 2; ++ks) {
                const int k0 = ks*32 + lg*8;
                #pragma unroll
                for (int j = 0; j < 8; ++j) {
                    const float rv = (1.f - ssk[row*NV + k0 + j]) * vw[k0 + j];
                    afrag[ks][j] = (short)f2bf(rv);
                }
            }
            #pragma unroll
            for (int n = 0; n < 4; ++n) {
                const int col = wn*64 + n*16 + l15;
                f32x4 acc = {0.f, 0.f, 0.f, 0.f};
                #pragma unroll
                for (int ks = 0; ks < 2; ++ks) {
                    const short8 bfr = *(const short8*)&s_At[col*72 + ks*32 + lg*8];
                    acc = __builtin_amdgcn_mfma_f32_16x16x32_bf16(afrag[ks], bfr, acc, 0, 0, 0);
                }
                #pragma unroll
                for (int rg = 0; rg < 4; ++rg)
                    s_r[(irow + rg)*136 + col] = f2bf(acc[rg]);
            }
        }
        __syncthreads();

        {
            short8 af2[4];
            #pragma unroll
            for (int ks = 0; ks < 4; ++ks)
                af2[ks] = *(const short8*)&s_r[(wm*16 + l15)*136 + ks*32 + lg*8];
            #pragma unroll
            for (int n = 0; n < 4; ++n) {
                const int col = wn*64 + n*16 + l15;
                f32x4 acc = {0.f, 0.f, 0.f, 0.f};
                #pragma unroll
                for (int ks = 0; ks < 4; ++ks) {
                    const short8 bfr = *(const short8*)&s_rWt[col*136 + ks*32 + lg*8];
                    acc = __builtin_amdgcn_mfma_f32_16x16x32_bf16(af2[ks], bfr, acc, 0, 0, 0);
                }
                const float rbv = rb[l*TW + col];
                short4v pk;
                #pragma unroll
                for (int rg = 0; rg < 4; ++rg) {
                    areg[n][rg] += fmaxf(acc[rg] + rbv, 0.f);
                    sreg[n][rg] += areg[n][rg];
                    pk[rg] = (short)f2bf(areg[n][rg]);
                }
                *(short4v*)&s_At[col*72 + irow] = pk;
            }
        }
        __syncthreads();
    }

    float p[4];
    #pragma unroll
    for (int n = 0; n < 4; ++n) {
        float acc = 0.f;
        #pragma unroll
        for (int rg = 0; rg < 4; ++rg) acc += s_wl[irow + rg] * sreg[n][rg];
        acc += __shfl_xor(acc, 16, 64);
        acc += __shfl_xor(acc, 32, 64);
        p[n] = acc;
    }
    if (lg == 0) {
        #pragma unroll
        for (int n = 0; n < 4; ++n)
            s_fin[wm*128 + wn*64 + n*16 + l15] = p[n];
    }
    __syncthreads();

    if (tid < 128) {
        const int w = tid;
        const float tot = s_fin[w] + s_fin[128 + w] + s_fin[256 + w] + s_fin[384 + w];
        float pw = (g_ws[b*TW + w] + tot) * fW[w];
        #pragma unroll
        for (int o = 32; o > 0; o >>= 1) pw += __shfl_down(pw, o, 64);
        if ((tid & 63) == 0) s_red[tid >> 6] = pw;
    }
    __syncthreads();
    if (tid == 0) out[b] = s_red[0] + s_red[1] + fb[0];
}

extern "C" void kernel_launch(void* const* d_in, const int* in_sizes, int n_in,
                              void* d_out, int out_size, void* d_ws, size_t ws_size,
                              hipStream_t stream) {
    const float* coords  = (const float*)d_in[0];
    const float* coordsp = (const float*)d_in[1];
    const float* scatk   = (const float*)d_in[2];
    const float* pos     = (const float*)d_in[3];
    const float* sigma   = (const float*)d_in[4];
    const float* vel     = (const float*)d_in[5];
    const float* vw      = (const float*)d_in[6];
    const float* ssk     = (const float*)d_in[7];
    const float* aW0 = (const float*)d_in[8];
    const float* ab0 = (const float*)d_in[9];
    const float* aW1 = (const float*)d_in[10];
    const float* ab1 = (const float*)d_in[11];
    const float* aW2 = (const float*)d_in[12];
    const float* ab2 = (const float*)d_in[13];
    const float* tW0 = (const float*)d_in[14];
    const float* tb0 = (const float*)d_in[15];
    const float* tW1 = (const float*)d_in[16];
    const float* tb1 = (const float*)d_in[17];
    const float* tW2 = (const float*)d_in[18];
    const float* tb2 = (const float*)d_in[19];
    const float* rW  = (const float*)d_in[20];
    const float* rb  = (const float*)d_in[21];
    const float* fW  = (const float*)d_in[22];
    const float* fb  = (const float*)d_in[23];
    float* out = (float*)d_out;

    float* ws = (float*)d_ws;
    float* coeff_ws = ws;                    // NQ floats, padded
    float* cur_ws   = ws + 4224;             // B*NV*TW floats
    float* g_ws     = cur_ws + B*NV*TW;      // B*TW floats

    hipLaunchKernelGGL(coeff_kernel, dim3(NQ/4), dim3(512), 0, stream,
        coords, vel, pos, sigma, aW0, ab0, aW1, ab1, aW2, ab2, coeff_ws);
    hipLaunchKernelGGL(transport_kernel, dim3(NQ/64), dim3(512), 0, stream,
        coords, coordsp, vel, tW0, tb0, tW1, tb1, tW2, tb2, coeff_ws, cur_ws, g_ws);
    hipLaunchKernelGGL(scatter_kernel, dim3(B), dim3(512), 0, stream,
        scatk, vw, ssk, rW, rb, fW, fb, cur_ws, g_ws, out);
}

// Round 21
// 68.294 us; speedup vs baseline: 1.8738x; 1.2414x over previous
//
#include <hip/hip_runtime.h>
#include <hip/hip_bf16.h>
#include <math.h>

#define D 2
#define B 64
#define P 512
#define NV 64
#define H 64
#define TW 128
#define NQ (B*NV + B)   // 4160

typedef short short8 __attribute__((ext_vector_type(8)));
typedef short short4v __attribute__((ext_vector_type(4)));
typedef float f32x4 __attribute__((ext_vector_type(4)));
typedef int   int4v  __attribute__((ext_vector_type(4)));

static __device__ __forceinline__ unsigned short f2bf(float f) {
    unsigned int u = __builtin_bit_cast(unsigned int, f);
    u += 0x7FFFu + ((u >> 16) & 1u);          // RNE
    return (unsigned short)(u >> 16);
}
static __device__ __forceinline__ unsigned int pk2bf(float a, float b) {
    __hip_bfloat162 h = __float22bfloat162_rn(make_float2(a, b));  // v_cvt_pk_bf16_f32
    unsigned int u;
    __builtin_memcpy(&u, &h, 4);              // a -> low 16, b -> high 16
    return u;
}

// ---------------- Kernel A: coeff (attention) ----------------
// FINAL = R16 (best measured: coeff 58.2us, total 68.35us).
// 2 queries per 256-thread block (2 waves each), 16 passes of 16 positions,
// geometry software-pipelined one pass ahead. w4/w5/b1/w2 + per-query base
// in LDS (broadcast reads); only afrag register-pinned. Wave-pair-redundant
// softmax. __launch_bounds__(256,3) proven no-spill; NEVER (256,4) nor
// larger blocks (R4/R7/R17/R19/R20: spill or occupancy regression).
__global__ __launch_bounds__(256, 3) void coeff_kernel(
    const float* __restrict__ coords, const float* __restrict__ vel,
    const float* __restrict__ pos, const float* __restrict__ sigma,
    const float* __restrict__ aW0, const float* __restrict__ ab0,
    const float* __restrict__ aW1, const float* __restrict__ ab1,
    const float* __restrict__ aW2, const float* __restrict__ ab2,
    float* __restrict__ coeff_out)
{
    __shared__ unsigned short s_w1t[64*72];   // aW1^T [n][k] bf16, stride 72
    __shared__ float2 s_pos[P];
    __shared__ float  s_logit[2*P];           // per-query 512 masked logits
    __shared__ float  s_cw[4*64];             // w4 | w5 | b1 | w2 (query-indep)
    __shared__ float  s_base[2][64];          // per-query collapsed layer1 base

    const int tid  = threadIdx.x;
    const int lane = tid & 63, wid = tid >> 6;
    const int l15 = lane & 15, lg = lane >> 4;
    const int qi   = wid >> 1;                // query index within block (0/1)
    const int half = wid & 1;                 // position half (0: 0-255, 1: 256-511)
    const int q = blockIdx.x*2 + qi;

    // ---- block-wide staging
    for (int i = tid; i < H*H; i += 256) {
        const int k = i >> 6, n = i & 63;
        s_w1t[n*72 + k] = f2bf(aW1[i]);
    }
    {
        const float4 p4 = ((const float4*)pos)[tid];
        *(float4*)&s_pos[tid*2] = p4;
    }
    if (tid < 64)        s_cw[tid] = aW0[256 + tid];        // w4
    else if (tid < 128)  s_cw[tid] = aW0[320 + (tid-64)];   // w5
    else if (tid < 192)  s_cw[tid] = ab1[tid-128];          // b1
    else                 s_cw[tid] = aW2[tid-192];          // w2

    // ---- per-wave query scalars
    float x0, x1, v0, v1;
    {
        int b;
        if (q < B*NV) { b = q >> 6; const int j = q & 63;
            v0 = vel[2*j]; v1 = vel[2*j+1];
        } else { b = q - B*NV;
            v0 = coords[4*b+2]; v1 = coords[4*b+3];
        }
        x0 = coords[4*b]; x1 = coords[4*b+1];
    }
    const float rinv = rsqrtf(v0*v0 + v1*v1 + 1e-16f);
    const float a0 = v0*rinv, a1 = v1*rinv;

    // ---- per-query collapsed base (computed once by the half==0 wave)
    if (half == 0) {
        const int k = lane;
        s_base[qi][k] = ab0[k] + x0*aW0[k] + x1*aW0[64+k]
                      + v0*aW0[128+k] + v1*aW0[192+k];
    }
    __syncthreads();

    // ---- A fragments: aW1^T rows = n, persistent (only pinned register set)
    short8 afrag[4][2];
    #pragma unroll
    for (int nt = 0; nt < 4; ++nt)
        #pragma unroll
        for (int ks = 0; ks < 2; ++ks)
            afrag[nt][ks] = *(const short8*)&s_w1t[(nt*16 + l15)*72 + ks*32 + lg*8];
    #pragma unroll
    for (int nt = 0; nt < 4; ++nt)
        asm volatile("" : "+v"(afrag[nt][0]), "+v"(afrag[nt][1]));

    const float* bq = s_base[qi];
    const int k0 = lg*8;

    // ---- 16 passes of 16 positions; geometry software-pipelined one ahead
    float pl, al;
    {
        const float2 p0v = s_pos[half*256 + l15];
        const float rx = x0 - p0v.x, ry = x1 - p0v.y;
        const float rd = __builtin_amdgcn_sqrtf(rx*rx + ry*ry + 1e-16f);
        pl = rx*a0 + ry*a1;
        al = __fdividef(pl, rd + 1e-8f);
    }
    for (int ps = 0; ps < 16; ++ps) {
        const int prow = half*256 + ps*16 + l15;
        float pln = pl, aln = al;
        if (ps < 15) {
            const float2 nxt = s_pos[prow + 16];
            const float rxn = x0 - nxt.x, ryn = x1 - nxt.y;
            const float rdn = __builtin_amdgcn_sqrtf(rxn*rxn + ryn*ryn + 1e-16f);
            pln = rxn*a0 + ryn*a1;
            aln = __fdividef(pln, rdn + 1e-8f);
        }

        // layer1 from LDS (broadcast f32x4 reads) directly into B-fragments
        const f32x4 w4A = *(const f32x4*)&s_cw[k0];
        const f32x4 w4B = *(const f32x4*)&s_cw[k0+4];
        const f32x4 w4C = *(const f32x4*)&s_cw[k0+32];
        const f32x4 w4D = *(const f32x4*)&s_cw[k0+36];
        const f32x4 w5A = *(const f32x4*)&s_cw[64+k0];
        const f32x4 w5B = *(const f32x4*)&s_cw[64+k0+4];
        const f32x4 w5C = *(const f32x4*)&s_cw[64+k0+32];
        const f32x4 w5D = *(const f32x4*)&s_cw[64+k0+36];
        const f32x4 bA  = *(const f32x4*)&bq[k0];
        const f32x4 bB  = *(const f32x4*)&bq[k0+4];
        const f32x4 bC  = *(const f32x4*)&bq[k0+32];
        const f32x4 bD  = *(const f32x4*)&bq[k0+36];

        f32x4 rA, rB, rC, rD;
        #pragma unroll
        for (int c = 0; c < 4; ++c) {
            rA[c] = fmaxf(fmaf(pl, w5A[c], fmaf(al, w4A[c], bA[c])), 0.f);
            rB[c] = fmaxf(fmaf(pl, w5B[c], fmaf(al, w4B[c], bB[c])), 0.f);
            rC[c] = fmaxf(fmaf(pl, w5C[c], fmaf(al, w4C[c], bC[c])), 0.f);
            rD[c] = fmaxf(fmaf(pl, w5D[c], fmaf(al, w4D[c], bD[c])), 0.f);
        }
        int4v wlo, whi;
        wlo[0] = (int)pk2bf(rA[0], rA[1]);
        wlo[1] = (int)pk2bf(rA[2], rA[3]);
        wlo[2] = (int)pk2bf(rB[0], rB[1]);
        wlo[3] = (int)pk2bf(rB[2], rB[3]);
        whi[0] = (int)pk2bf(rC[0], rC[1]);
        whi[1] = (int)pk2bf(rC[2], rC[3]);
        whi[2] = (int)pk2bf(rD[0], rD[1]);
        whi[3] = (int)pk2bf(rD[2], rD[3]);
        const short8 bf0 = __builtin_bit_cast(short8, wlo);
        const short8 bf1 = __builtin_bit_cast(short8, whi);

        float ssum = 0.f;
        #pragma unroll
        for (int nt = 0; nt < 4; ++nt) {
            const int n0 = nt*16 + lg*4;
            f32x4 acc = *(const f32x4*)&s_cw[128 + n0];   // b1 C-init (LDS broadcast)
            acc = __builtin_amdgcn_mfma_f32_16x16x32_bf16(afrag[nt][0], bf0, acc, 0, 0, 0);
            acc = __builtin_amdgcn_mfma_f32_16x16x32_bf16(afrag[nt][1], bf1, acc, 0, 0, 0);
            const f32x4 w2x = *(const f32x4*)&s_cw[192 + n0];
            ssum += fmaxf(acc[0], 0.f) * w2x[0];
            ssum += fmaxf(acc[1], 0.f) * w2x[1];
            ssum += fmaxf(acc[2], 0.f) * w2x[2];
            ssum += fmaxf(acc[3], 0.f) * w2x[3];
        }
        ssum += __shfl_xor(ssum, 16, 64);
        ssum += __shfl_xor(ssum, 32, 64);
        if (lane < 16) s_logit[qi*512 + prow] = (pl > 0.f) ? ssum : -1e30f;
        pl = pln; al = aln;
    }
    __syncthreads();

    // ---- softmax + sigma dot (wave-pair-redundant, bit-identical)
    const float* lgb = &s_logit[qi*512];
    const float4 l0 = *(const float4*)&lgb[lane*8];
    const float4 l1 = *(const float4*)&lgb[lane*8 + 4];
    float m = fmaxf(fmaxf(fmaxf(l0.x, l0.y), fmaxf(l0.z, l0.w)),
                    fmaxf(fmaxf(l1.x, l1.y), fmaxf(l1.z, l1.w)));
    #pragma unroll
    for (int o = 32; o > 0; o >>= 1) m = fmaxf(m, __shfl_xor(m, o, 64));

    const float4 g0 = *(const float4*)&sigma[lane*8];
    const float4 g1 = *(const float4*)&sigma[lane*8 + 4];
    float S = 0.f, T = 0.f, e;
    e = __expf(l0.x - m); S += e; T += e*g0.x;
    e = __expf(l0.y - m); S += e; T += e*g0.y;
    e = __expf(l0.z - m); S += e; T += e*g0.z;
    e = __expf(l0.w - m); S += e; T += e*g0.w;
    e = __expf(l1.x - m); S += e; T += e*g1.x;
    e = __expf(l1.y - m); S += e; T += e*g1.y;
    e = __expf(l1.z - m); S += e; T += e*g1.z;
    e = __expf(l1.w - m); S += e; T += e*g1.w;
    #pragma unroll
    for (int o = 32; o > 0; o >>= 1) { S += __shfl_xor(S, o, 64); T += __shfl_xor(T, o, 64); }
    if (lane == 0 && half == 0) coeff_out[q] = __expf(-(T / S));
}

// ---------------- Kernel B: transport MLP (MFMA, 64 queries/block) ----------------
__global__ __launch_bounds__(512) void transport_kernel(
    const float* __restrict__ coords, const float* __restrict__ coordsp,
    const float* __restrict__ vel,
    const float* __restrict__ tW0, const float* __restrict__ tb0,
    const float* __restrict__ tW1, const float* __restrict__ tb1,
    const float* __restrict__ tW2, const float* __restrict__ tb2,
    const float* __restrict__ coeff_ws, float* __restrict__ cur_ws,
    float* __restrict__ g_ws)
{
    __shared__ unsigned short s_w0t[128*40];
    __shared__ unsigned short s_wt[128*136];
    __shared__ unsigned short s_in[64*40];
    __shared__ unsigned short s_ha[64*136];
    __shared__ unsigned short s_hb[64*136];
    __shared__ float s_b[3*128];

    const int tid = threadIdx.x, g = blockIdx.x;
    const int lane = tid & 63, wid = tid >> 6;
    const int wm = wid & 3, wn = wid >> 2;
    const int l15 = lane & 15, lg = lane >> 4;
    const int irow = wm*16 + lg*4;
    const int qbase = g*64;

    for (int i = tid; i < 128*40; i += 512) {
        const int t = i / 40, k = i % 40;
        s_w0t[i] = (k < 9) ? f2bf(tW0[k*TW + t]) : 0;
    }
    for (int i = tid; i < 64*40; i += 512) s_in[i] = 0;
    {
        const int n = tid & 127, u0 = (tid >> 7)*4;
        #pragma unroll
        for (int k8 = 0; k8 < 8; ++k8) {
            const int u = u0 + 16*k8;
            short4v pk;
            #pragma unroll
            for (int c = 0; c < 4; ++c) pk[c] = (short)f2bf(tW1[(u+c)*TW + n]);
            *(short4v*)&s_wt[n*136 + u] = pk;
        }
    }
    if (tid < 128) { s_b[tid] = tb0[tid]; s_b[128+tid] = tb1[tid]; s_b[256+tid] = tb2[tid]; }
    __syncthreads();

    if (tid < 64) {
        const int q = qbase + tid;
        int b; float v0, v1;
        if (q < B*NV) { b = q >> 6; const int j = q & 63;
            v0 = vel[2*j]; v1 = vel[2*j+1];
        } else { b = q - B*NV;
            v0 = coords[4*b+2]; v1 = coords[4*b+3];
        }
        unsigned short* r = &s_in[tid*40];
        r[0] = f2bf(coords[4*b]);   r[1] = f2bf(coords[4*b+1]);
        r[2] = f2bf(v0);            r[3] = f2bf(v1);
        r[4] = f2bf(coordsp[4*b]);  r[5] = f2bf(coordsp[4*b+1]);
        r[6] = f2bf(coordsp[4*b+2]);r[7] = f2bf(coordsp[4*b+3]);
        r[8] = f2bf(coeff_ws[q]);
    }
    __syncthreads();

    {
        const short8 a0 = *(const short8*)&s_in[(wm*16 + l15)*40 + lg*8];
        #pragma unroll
        for (int nt = 0; nt < 4; ++nt) {
            const int col = wn*64 + nt*16 + l15;
            const short8 b0f = *(const short8*)&s_w0t[col*40 + lg*8];
            const float bias = s_b[col];
            f32x4 acc = { bias, bias, bias, bias };
            acc = __builtin_amdgcn_mfma_f32_16x16x32_bf16(a0, b0f, acc, 0, 0, 0);
            #pragma unroll
            for (int rg = 0; rg < 4; ++rg)
                s_ha[(irow + rg)*136 + col] = f2bf(fmaxf(acc[rg], 0.f));
        }
    }
    __syncthreads();

    {
        short8 af[4];
        #pragma unroll
        for (int ks = 0; ks < 4; ++ks)
            af[ks] = *(const short8*)&s_ha[(wm*16 + l15)*136 + ks*32 + lg*8];
        #pragma unroll
        for (int nt = 0; nt < 4; ++nt) {
            const int col = wn*64 + nt*16 + l15;
            const float bias = s_b[128 + col];
            f32x4 acc = { bias, bias, bias, bias };
            #pragma unroll
            for (int ks = 0; ks < 4; ++ks) {
                const short8 bfr = *(const short8*)&s_wt[col*136 + ks*32 + lg*8];
                acc = __builtin_amdgcn_mfma_f32_16x16x32_bf16(af[ks], bfr, acc, 0, 0, 0);
            }
            #pragma unroll
            for (int rg = 0; rg < 4; ++rg)
                s_hb[(irow + rg)*136 + col] = f2bf(fmaxf(acc[rg], 0.f));
        }
    }
    __syncthreads();

    {
        const int n = tid & 127, u0 = (tid >> 7)*4;
        #pragma unroll
        for (int k8 = 0; k8 < 8; ++k8) {
            const int u = u0 + 16*k8;
            short4v pk;
            #pragma unroll
            for (int c = 0; c < 4; ++c) pk[c] = (short)f2bf(tW2[(u+c)*TW + n]);
            *(short4v*)&s_wt[n*136 + u] = pk;
        }
    }
    __syncthreads();

    {
        short8 af[4];
        #pragma unroll
        for (int ks = 0; ks < 4; ++ks)
            af[ks] = *(const short8*)&s_hb[(wm*16 + l15)*136 + ks*32 + lg*8];
        #pragma unroll
        for (int nt = 0; nt < 4; ++nt) {
            const int col = wn*64 + nt*16 + l15;
            const float bias = s_b[256 + col];
            f32x4 acc = { bias, bias, bias, bias };
            #pragma unroll
            for (int ks = 0; ks < 4; ++ks) {
                const short8 bfr = *(const short8*)&s_wt[col*136 + ks*32 + lg*8];
                acc = __builtin_amdgcn_mfma_f32_16x16x32_bf16(af[ks], bfr, acc, 0, 0, 0);
            }
            #pragma unroll
            for (int rg = 0; rg < 4; ++rg) {
                const float o = __expf(fmaxf(acc[rg], 0.f));
                const int q = qbase + irow + rg;
                if (q < B*NV) cur_ws[q*TW + col] = o;
                else          g_ws[(q - B*NV)*TW + col] = o;
            }
        }
    }
}

// ---------------- Kernel C: scattering recursion + output (MFMA) ----------------
__global__ __launch_bounds__(512) void scatter_kernel(
    const float* __restrict__ scat_k, const float* __restrict__ vw,
    const float* __restrict__ ssk,
    const float* __restrict__ rW, const float* __restrict__ rb,
    const float* __restrict__ fW, const float* __restrict__ fb,
    const float* __restrict__ cur_ws, const float* __restrict__ g_ws,
    float* __restrict__ out)
{
    __shared__ unsigned short s_At[128*72];
    __shared__ unsigned short s_r[64*136];
    __shared__ unsigned short s_rWt[128*136];
    __shared__ float s_wl[NV];
    __shared__ float s_fin[4*128];
    __shared__ float s_red[2];

    const int tid = threadIdx.x, b = blockIdx.x;
    const int lane = tid & 63, wid = tid >> 6;
    const int wm = wid & 3, wn = wid >> 2;
    const int l15 = lane & 15, lg = lane >> 4;
    const int irow = wm*16 + lg*4;

    if (tid < NV) s_wl[tid] = (1.f - scat_k[b*NV + tid]) * vw[tid];

    {
        const int w = tid & 127, j0 = tid >> 7;
        #pragma unroll
        for (int k = 0; k < 16; ++k) {
            const int j = j0 + 4*k;
            s_At[w*72 + j] = f2bf(cur_ws[(b*NV + j)*TW + w]);
        }
    }

    float areg[4][4], sreg[4][4];
    #pragma unroll
    for (int n = 0; n < 4; ++n) {
        const int wcol = wn*64 + n*16 + l15;
        #pragma unroll
        for (int rg = 0; rg < 4; ++rg) {
            const float v = cur_ws[(b*NV + irow + rg)*TW + wcol];
            areg[n][rg] = v; sreg[n][rg] = v;
        }
    }

    for (int l = 0; l < 2; ++l) {
        {
            const float* rWl = rW + l*TW*TW;
            const int w = tid & 127, u0 = (tid >> 7)*4;
            #pragma unroll
            for (int k = 0; k < 8; ++k) {
                const int u = u0 + 16*k;
                short4v pk;
                #pragma unroll
                for (int c = 0; c < 4; ++c) pk[c] = (short)f2bf(rWl[(u+c)*TW + w]);
                *(short4v*)&s_rWt[w*136 + u] = pk;
            }
        }
        __syncthreads();

        {
            short8 afrag[2];
            const int row = wm*16 + l15;
            #pragma unroll
            for (int ks = 0; ks < 2; ++ks) {
                const int k0 = ks*32 + lg*8;
                #pragma unroll
                for (int j = 0; j < 8; ++j) {
                    const float rv = (1.f - ssk[row*NV + k0 + j]) * vw[k0 + j];
                    afrag[ks][j] = (short)f2bf(rv);
                }
            }
            #pragma unroll
            for (int n = 0; n < 4; ++n) {
                const int col = wn*64 + n*16 + l15;
                f32x4 acc = {0.f, 0.f, 0.f, 0.f};
                #pragma unroll
                for (int ks = 0; ks < 2; ++ks) {
                    const short8 bfr = *(const short8*)&s_At[col*72 + ks*32 + lg*8];
                    acc = __builtin_amdgcn_mfma_f32_16x16x32_bf16(afrag[ks], bfr, acc, 0, 0, 0);
                }
                #pragma unroll
                for (int rg = 0; rg < 4; ++rg)
                    s_r[(irow + rg)*136 + col] = f2bf(acc[rg]);
            }
        }
        __syncthreads();

        {
            short8 af2[4];
            #pragma unroll
            for (int ks = 0; ks < 4; ++ks)
                af2[ks] = *(const short8*)&s_r[(wm*16 + l15)*136 + ks*32 + lg*8];
            #pragma unroll
            for (int n = 0; n < 4; ++n) {
                const int col = wn*64 + n*16 + l15;
                f32x4 acc = {0.f, 0.f, 0.f, 0.f};
                #pragma unroll
                for (int ks = 0; ks < 4; ++ks) {
                    const short8 bfr = *(const short8*)&s_rWt[col*136 + ks*32 + lg*8];
                    acc = __builtin_amdgcn_mfma_f32_16x16x32_bf16(af2[ks], bfr, acc, 0, 0, 0);
                }
                const float rbv = rb[l*TW + col];
                short4v pk;
                #pragma unroll
                for (int rg = 0; rg < 4; ++rg) {
                    areg[n][rg] += fmaxf(acc[rg] + rbv, 0.f);
                    sreg[n][rg] += areg[n][rg];
                    pk[rg] = (short)f2bf(areg[n][rg]);
                }
                *(short4v*)&s_At[col*72 + irow] = pk;
            }
        }
        __syncthreads();
    }

    float p[4];
    #pragma unroll
    for (int n = 0; n < 4; ++n) {
        float acc = 0.f;
        #pragma unroll
        for (int rg = 0; rg < 4; ++rg) acc += s_wl[irow + rg] * sreg[n][rg];
        acc += __shfl_xor(acc, 16, 64);
        acc += __shfl_xor(acc, 32, 64);
        p[n] = acc;
    }
    if (lg == 0) {
        #pragma unroll
        for (int n = 0; n < 4; ++n)
            s_fin[wm*128 + wn*64 + n*16 + l15] = p[n];
    }
    __syncthreads();

    if (tid < 128) {
        const int w = tid;
        const float tot = s_fin[w] + s_fin[128 + w] + s_fin[256 + w] + s_fin[384 + w];
        float pw = (g_ws[b*TW + w] + tot) * fW[w];
        #pragma unroll
        for (int o = 32; o > 0; o >>= 1) pw += __shfl_down(pw, o, 64);
        if ((tid & 63) == 0) s_red[tid >> 6] = pw;
    }
    __syncthreads();
    if (tid == 0) out[b] = s_red[0] + s_red[1] + fb[0];
}

extern "C" void kernel_launch(void* const* d_in, const int* in_sizes, int n_in,
                              void* d_out, int out_size, void* d_ws, size_t ws_size,
                              hipStream_t stream) {
    const float* coords  = (const float*)d_in[0];
    const float* coordsp = (const float*)d_in[1];
    const float* scatk   = (const float*)d_in[2];
    const float* pos     = (const float*)d_in[3];
    const float* sigma   = (const float*)d_in[4];
    const float* vel     = (const float*)d_in[5];
    const float* vw      = (const float*)d_in[6];
    const float* ssk     = (const float*)d_in[7];
    const float* aW0 = (const float*)d_in[8];
    const float* ab0 = (const float*)d_in[9];
    const float* aW1 = (const float*)d_in[10];
    const float* ab1 = (const float*)d_in[11];
    const float* aW2 = (const float*)d_in[12];
    const float* ab2 = (const float*)d_in[13];
    const float* tW0 = (const float*)d_in[14];
    const float* tb0 = (const float*)d_in[15];
    const float* tW1 = (const float*)d_in[16];
    const float* tb1 = (const float*)d_in[17];
    const float* tW2 = (const float*)d_in[18];
    const float* tb2 = (const float*)d_in[19];
    const float* rW  = (const float*)d_in[20];
    const float* rb  = (const float*)d_in[21];
    const float* fW  = (const float*)d_in[22];
    const float* fb  = (const float*)d_in[23];
    float* out = (float*)d_out;

    float* ws = (float*)d_ws;
    float* coeff_ws = ws;                    // NQ floats, padded
    float* cur_ws   = ws + 4224;             // B*NV*TW floats
    float* g_ws     = cur_ws + B*NV*TW;      // B*TW floats

    hipLaunchKernelGGL(coeff_kernel, dim3(NQ/2), dim3(256), 0, stream,
        coords, vel, pos, sigma, aW0, ab0, aW1, ab1, aW2, ab2, coeff_ws);
    hipLaunchKernelGGL(transport_kernel, dim3(NQ/64), dim3(512), 0, stream,
        coords, coordsp, vel, tW0, tb0, tW1, tb1, tW2, tb2, coeff_ws, cur_ws, g_ws);
    hipLaunchKernelGGL(scatter_kernel, dim3(B), dim3(512), 0, stream,
        scatk, vw, ssk, rW, rb, fW, fb, cur_ws, g_ws, out);
}